// Round 14
// baseline (366.232 us; speedup 1.0000x reference)
//
#include <hip/hip_runtime.h>

namespace {

constexpr int N_NODES = 100000;
constexpr int N_EDGES = 1600000;
constexpr int HDIM = 128;
constexpr int CDIM = 18;

constexpr int NW = N_NODES / 4;            // 25000 packed-byte words (100 KB LDS)
constexpr int S_IN = 128;                  // dst-histogram slices
constexpr int S_OUT = 64;                  // src-histogram slices
constexpr int EPB_IN = N_EDGES / S_IN;     // 12500
constexpr int EPB_OUT = N_EDGES / S_OUT;   // 25000
constexpr int RB = (NW + 255) / 256;       // reduce/scan blocks (1024 nodes each) = 98
constexpr int WTB = 3 * HDIM * HDIM / 1024;  // Wt conversion blocks (1024 thr) = 48
constexpr int W5B = 32 * HDIM / 1024;        // W5t conversion blocks = 4

using f4 = __attribute__((ext_vector_type(4))) float;
using s8v = __attribute__((ext_vector_type(8))) short;   // 8 bf16 (4 VGPRs), MFMA A/B frag
using us4 = __attribute__((ext_vector_type(4))) unsigned short;
using us8 = __attribute__((ext_vector_type(8))) unsigned short;
using uint = unsigned int;
using ushort = unsigned short;

// bf16 pack/unpack (RNE on pack; unpack is exact bit-splicing)
__device__ __forceinline__ ushort bf16_of(float f) {
    uint u = __float_as_uint(f);
    return (ushort)((u + 0x7FFFu + ((u >> 16) & 1u)) >> 16);
}
__device__ __forceinline__ float f_of_bf(ushort u) {
    return __uint_as_float((uint)u << 16);
}
__device__ __forceinline__ f4 f4_of_bf4(uint lo, uint hi) {
    f4 r;
    r.x = __uint_as_float(lo << 16);
    r.y = __uint_as_float(lo & 0xFFFF0000u);
    r.z = __uint_as_float(hi << 16);
    r.w = __uint_as_float(hi & 0xFFFF0000u);
    return r;
}

// ---------------- histograms + (free-riding) weight conversions ----------------
// Blocks 0..191: packed-byte histograms (100 KB LDS, 1 block/CU).
// Blocks 192..239: W2-4 -> bf16^T. Blocks 240..243: W5 -> bf16^T padded 32x128.

__global__ __launch_bounds__(1024) void hist_kernel(const int* __restrict__ src,
                                                    const int* __restrict__ dst,
                                                    uint* __restrict__ part_out,
                                                    uint* __restrict__ part_in,
                                                    const float* __restrict__ W2,
                                                    const float* __restrict__ W3,
                                                    const float* __restrict__ W4,
                                                    ushort* __restrict__ Wt,
                                                    const float* __restrict__ W5,
                                                    ushort* __restrict__ W5t) {
    int b = blockIdx.x;
    if (b >= S_OUT + S_IN) {
        int cb = b - (S_OUT + S_IN);
        if (cb < WTB) {
            int idx = cb * 1024 + threadIdx.x;  // 48*1024 = 3*128*128
            int which = idx >> 14;
            int r = idx & 16383;
            const float* W = which == 0 ? W2 : (which == 1 ? W3 : W4);
            int nn = r >> 7, k = r & 127;
            Wt[idx] = bf16_of(W[k * HDIM + nn]);
        } else {
            int idx = (cb - WTB) * 1024 + threadIdx.x;  // 4*1024 = 32*128
            int nn = idx >> 7, k = idx & 127;
            W5t[idx] = (nn < CDIM) ? bf16_of(W5[k * CDIM + nn]) : (ushort)0;
        }
        return;
    }
    __shared__ uint hist[NW];
    for (int i = threadIdx.x; i < NW; i += 1024) hist[i] = 0u;
    __syncthreads();
    const int* idx;
    uint* part;
    int beg, cnt;
    if (b < S_OUT) {
        idx = src;
        part = part_out + (size_t)b * NW;
        beg = b * EPB_OUT;
        cnt = EPB_OUT;
    } else {
        int b2 = b - S_OUT;
        idx = dst;
        part = part_in + (size_t)b2 * NW;
        beg = b2 * EPB_IN;
        cnt = EPB_IN;
    }
    for (int i = threadIdx.x; i < cnt; i += 1024) {
        int d = idx[beg + i];
        atomicAdd(&hist[d >> 2], 1u << ((d & 3) * 8));
    }
    __syncthreads();
    for (int i = threadIdx.x; i < NW; i += 1024) part[i] = hist[i];
}

// ---------------- reduce: partials -> per-slice byte offsets (in place) + deg4 + coeffs
//                  + raw per-block sums + featb = bf16(feat * c_src) ----------------

__global__ __launch_bounds__(256) void reduce_kernel(uint* __restrict__ part_in,  // -> off_in
                                                     const uint* __restrict__ part_out,
                                                     uint* __restrict__ deg4,
                                                     float* __restrict__ c_src,
                                                     float* __restrict__ c_dst,
                                                     int* __restrict__ blk_sum,
                                                     const float* __restrict__ feat,
                                                     us8* __restrict__ featb) {
    __shared__ int ssum[256];
    int t = threadIdx.x;
    int w = blockIdx.x * 256 + t;
    uint sin = 0u;
    int tot = 0;
    if (w < NW) {
        for (int s = 0; s < S_IN; ++s) {
            size_t p = (size_t)s * NW + w;
            uint c = part_in[p];
            part_in[p] = sin;  // exclusive prefix over slices, packed bytes
            sin += c;
        }
        uint sout = 0u;
        for (int s = 0; s < S_OUT; ++s) sout += part_out[(size_t)s * NW + w];
        deg4[w] = sin;
        f4 F[6];
        const f4* fp = (const f4*)(feat + (size_t)w * 24);
#pragma unroll
        for (int r = 0; r < 6; ++r) F[r] = fp[r];
#pragma unroll
        for (int q = 0; q < 4; ++q) {
            int v = w * 4 + q;
            int di = (sin >> (q * 8)) & 255;
            int dq = (sout >> (q * 8)) & 255;
            c_dst[v] = di > 0 ? rsqrtf((float)di) : 0.0f;
            float cs = dq > 0 ? rsqrtf((float)dq) : 0.0f;
            c_src[v] = cs;
            us8 o;
#pragma unroll
            for (int k = 0; k < 6; ++k) {
                int idx = q * 6 + k;
                o[k] = bf16_of(F[idx >> 2][idx & 3] * cs);
            }
            o[6] = 0;
            o[7] = 0;
            featb[v] = o;
            tot += di;
        }
    }
    ssum[t] = tot;
    __syncthreads();
    for (int off = 128; off > 0; off >>= 1) {
        if (t < off) ssum[t] += ssum[t + off];
        __syncthreads();
    }
    if (t == 0) blk_sum[blockIdx.x] = ssum[0];
}

// ---------------- scan_final: self-scan raw blk_sums + local scan -> row_ptr (int4) ----------

__global__ __launch_bounds__(256) void scan_final_kernel(const uint* __restrict__ deg4,
                                                         const int* __restrict__ blk_sum,
                                                         int* __restrict__ row_ptr) {
    __shared__ int s[256];
    __shared__ int bs[128];
    int b = blockIdx.x, t = threadIdx.x;
    if (t < 128) bs[t] = (t < RB) ? blk_sum[t] : 0;
    __syncthreads();
    for (int off = 1; off < 128; off <<= 1) {
        int v = (t < 128 && t >= off) ? bs[t - off] : 0;
        __syncthreads();
        if (t < 128) bs[t] += v;
        __syncthreads();
    }
    int blk_off = (b == 0) ? 0 : bs[b - 1];
    int w = b * 256 + t;
    uint d = (w < NW) ? deg4[w] : 0u;
    int d0 = d & 255, d1 = (d >> 8) & 255, d2 = (d >> 16) & 255, d3 = d >> 24;
    int tot = d0 + d1 + d2 + d3;
    s[t] = tot;
    __syncthreads();
    for (int off = 1; off < 256; off <<= 1) {
        int u = (t >= off) ? s[t - off] : 0;
        __syncthreads();
        s[t] += u;
        __syncthreads();
    }
    if (w < NW) {
        int excl = blk_off + s[t] - tot;
        int4 rp;
        rp.x = excl;
        rp.y = excl + d0;
        rp.z = excl + d0 + d1;
        rp.w = excl + d0 + d1 + d2;
        ((int4*)row_ptr)[w] = rp;
    }
    if (b == 0 && t == 0) row_ptr[N_NODES] = N_EDGES;
}

// ---------------- CSR fill, atomic-free: pos = row_ptr + off[slice] + local rank ------------

__global__ __launch_bounds__(1024) void fill_kernel(const int* __restrict__ src,
                                                    const int* __restrict__ dst,
                                                    const uint* __restrict__ off_in,
                                                    const int* __restrict__ row_ptr,
                                                    int* __restrict__ csr_src) {
    __shared__ uint hist[NW];
    for (int i = threadIdx.x; i < NW; i += 1024) hist[i] = 0u;
    __syncthreads();
    int b = blockIdx.x;
    const uint* off = off_in + (size_t)b * NW;
    int beg = b * EPB_IN;
    for (int i = threadIdx.x; i < EPB_IN; i += 1024) {
        int e = beg + i;
        int d = dst[e];
        int sh = (d & 3) * 8;
        uint old = atomicAdd(&hist[d >> 2], 1u << sh);  // LDS, returns old -> unique rank
        int rank = (old >> sh) & 255;
        int base = (off[d >> 2] >> sh) & 255;
        csr_src[row_ptr[d] + base + rank] = src[e];
    }
}

// ================= MFMA transform helper (h in swizzled LDS, W from global) =================
// xw_out[node] = bf16( (h[node] @ W) * c_src[node] ). Wave w -> nodes base + w*16 + lm.

__device__ __forceinline__ void mfma_transform(const us8* __restrict__ hs,
                                               const ushort* __restrict__ Wt,
                                               const float* __restrict__ c_src,
                                               ushort* __restrict__ xw_out, int base, int n,
                                               int t) {
    int l = t & 63;
    int lm = l & 15, lg = l >> 4;
    int j = (t >> 6) * 16 + lm;
    int node = base + j;
    const s8v* hv = (const s8v*)hs;
    s8v hb0 = hv[j * 16 + (lg ^ lm)];
    s8v hb1 = hv[j * 16 + ((4 + lg) ^ lm)];
    s8v hb2 = hv[j * 16 + ((8 + lg) ^ lm)];
    s8v hb3 = hv[j * 16 + ((12 + lg) ^ lm)];
    f4 acc[8];
#pragma unroll
    for (int g = 0; g < 8; ++g) acc[g] = {0.f, 0.f, 0.f, 0.f};
#pragma unroll
    for (int g = 0; g < 8; ++g) {
        const s8v* wp = (const s8v*)(Wt + (size_t)(g * 16 + lm) * HDIM + lg * 8);
        acc[g] = __builtin_amdgcn_mfma_f32_16x16x32_bf16(wp[0], hb0, acc[g], 0, 0, 0);
        acc[g] = __builtin_amdgcn_mfma_f32_16x16x32_bf16(wp[4], hb1, acc[g], 0, 0, 0);
        acc[g] = __builtin_amdgcn_mfma_f32_16x16x32_bf16(wp[8], hb2, acc[g], 0, 0, 0);
        acc[g] = __builtin_amdgcn_mfma_f32_16x16x32_bf16(wp[12], hb3, acc[g], 0, 0, 0);
    }
    if (node < n) {
        float cs = c_src[node];
        ushort* orow = xw_out + (size_t)node * HDIM;
#pragma unroll
        for (int g = 0; g < 8; ++g) {
            us4 o;
            o.x = bf16_of(acc[g].x * cs);
            o.y = bf16_of(acc[g].y * cs);
            o.z = bf16_of(acc[g].z * cs);
            o.w = bf16_of(acc[g].w * cs);
            *(us4*)(orow + g * 16 + lg * 4) = o;
        }
    }
}

// ---------------- layer 1 fused: feat-gather + W1 micro-GEMM + W2 MFMA -> xw1 ----------------
// 64 nodes/block; feat rows are 16 B + L2-resident -> short gather, safe barrier tail.

__global__ __launch_bounds__(256) void layer1_kernel(
    const int* __restrict__ row_ptr, const int* __restrict__ csr_src,
    const us8* __restrict__ featb, const float* __restrict__ c_dst,
    const float* __restrict__ W1, const float* __restrict__ b1,
    const ushort* __restrict__ Wt2, const float* __restrict__ c_src,
    ushort* __restrict__ xw_out, int n) {
    __shared__ us8 hs[64 * 16];
    __shared__ float xs[64][6];
    int t = threadIdx.x;
    int base = blockIdx.x * 64;
#pragma unroll
    for (int r = 0; r < 4; ++r) {
        int j = r * 16 + (t >> 4);
        int lane = t & 15;
        int node = base + j;
        if (node < n) {
            int beg = row_ptr[node], end = row_ptr[node + 1];
            float a0 = 0.f, a1 = 0.f, a2 = 0.f, a3 = 0.f, a4 = 0.f, a5 = 0.f;
            for (int i = beg + lane; i < end; i += 16) {
                us8 u = featb[csr_src[i]];  // pre-scaled by c_src
                a0 += f_of_bf(u[0]);
                a1 += f_of_bf(u[1]);
                a2 += f_of_bf(u[2]);
                a3 += f_of_bf(u[3]);
                a4 += f_of_bf(u[4]);
                a5 += f_of_bf(u[5]);
            }
#pragma unroll
            for (int m = 8; m >= 1; m >>= 1) {
                a0 += __shfl_xor(a0, m);
                a1 += __shfl_xor(a1, m);
                a2 += __shfl_xor(a2, m);
                a3 += __shfl_xor(a3, m);
                a4 += __shfl_xor(a4, m);
                a5 += __shfl_xor(a5, m);
            }
            if (lane == 0) {
                float cd = c_dst[node];
                xs[j][0] = a0 * cd;
                xs[j][1] = a1 * cd;
                xs[j][2] = a2 * cd;
                xs[j][3] = a3 * cd;
                xs[j][4] = a4 * cd;
                xs[j][5] = a5 * cd;
            }
        } else if (lane == 0) {
#pragma unroll
            for (int k = 0; k < 6; ++k) xs[j][k] = 0.f;
        }
    }
    __syncthreads();
    // h1 = relu(agg6 @ W1 + b1), bf16 into swizzled LDS
    {
        int f = t & 127;
        int half = t >> 7;
        float w[6];
#pragma unroll
        for (int k = 0; k < 6; ++k) w[k] = W1[k * HDIM + f];
        float bv = b1[f];
        ushort* hsu = (ushort*)hs;
        int c16 = f >> 3, e = f & 7;
        for (int j = half * 32; j < half * 32 + 32; ++j) {
            float acc = bv;
#pragma unroll
            for (int k = 0; k < 6; ++k) acc += xs[j][k] * w[k];
            hsu[(j * 16 + (c16 ^ (j & 15))) * 8 + e] = bf16_of(fmaxf(acc, 0.0f));
        }
    }
    __syncthreads();
    mfma_transform(hs, Wt2, c_src, xw_out, base, n, t);
}

// ---------------- hidden GEMM via MFMA, 256-node tiles, swizzled W in LDS ----------------
// Swizzle: 16B-unit index u = row*16 + c stored at row*16 + (c ^ (row&7)) -> breaks the
// 16-way bank conflict of the naive layout (all lm-lanes same bank at 256 B row stride).

__global__ __launch_bounds__(256) void gemm128_mfma_kernel(const ushort* __restrict__ h,
                                                           const ushort* __restrict__ Wt,
                                                           const float* __restrict__ c_src,
                                                           ushort* __restrict__ xw, int n) {
    __shared__ ushort wlds[HDIM * HDIM];  // 32 KB
    int t = threadIdx.x;
    {
        const uint4* ws = (const uint4*)Wt;
        uint4* wd = (uint4*)wlds;
#pragma unroll
        for (int r = 0; r < 8; ++r) {
            int u = r * 256 + t;
            int swz = (u & ~15) | ((u & 15) ^ ((u >> 4) & 7));
            wd[swz] = ws[u];
        }
    }
    __syncthreads();
    int w = t >> 6;
    int l = t & 63;
    int lm = l & 15, lg = l >> 4;
    const s8v* wl = (const s8v*)wlds;
#pragma unroll
    for (int it = 0; it < 4; ++it) {
        int base = blockIdx.x * 256 + it * 64 + w * 16;
        if (base >= n) continue;  // n % 16 == 0 -> wave fully valid or fully out
        const s8v* hp = (const s8v*)(h + (size_t)(base + lm) * HDIM + lg * 8);
        s8v hb0 = hp[0];
        s8v hb1 = hp[4];
        s8v hb2 = hp[8];
        s8v hb3 = hp[12];
        f4 acc[8];
#pragma unroll
        for (int g = 0; g < 8; ++g) acc[g] = {0.f, 0.f, 0.f, 0.f};
#pragma unroll
        for (int g = 0; g < 8; ++g) {
            int row = g * 16 + lm;
            int rb = row * 16;
            int rk = row & 7;
            acc[g] = __builtin_amdgcn_mfma_f32_16x16x32_bf16(wl[rb + (lg ^ rk)], hb0, acc[g], 0, 0, 0);
            acc[g] = __builtin_amdgcn_mfma_f32_16x16x32_bf16(wl[rb + ((4 + lg) ^ rk)], hb1, acc[g], 0, 0, 0);
            acc[g] = __builtin_amdgcn_mfma_f32_16x16x32_bf16(wl[rb + ((8 + lg) ^ rk)], hb2, acc[g], 0, 0, 0);
            acc[g] = __builtin_amdgcn_mfma_f32_16x16x32_bf16(wl[rb + ((12 + lg) ^ rk)], hb3, acc[g], 0, 0, 0);
        }
        float cs = c_src[base + lm];
        ushort* orow = xw + (size_t)(base + lm) * HDIM;
#pragma unroll
        for (int g = 0; g < 8; ++g) {
            us4 o;
            o.x = bf16_of(acc[g].x * cs);
            o.y = bf16_of(acc[g].y * cs);
            o.z = bf16_of(acc[g].z * cs);
            o.w = bf16_of(acc[g].w * cs);
            *(us4*)(orow + g * 16 + lg * 4) = o;
        }
    }
}

// ================= gather helper =================

__device__ __forceinline__ us8 gather_node_row(const int* __restrict__ row_ptr,
                                               const int* __restrict__ csr_src,
                                               const uint4* __restrict__ xw4,
                                               const float* __restrict__ c_dst,
                                               const f4* __restrict__ b4p, int node, int lane) {
    int beg = row_ptr[node], end = row_ptr[node + 1];
    f4 z = {0.f, 0.f, 0.f, 0.f};
    f4 lo0 = z, lo1 = z, lo2 = z, lo3 = z, hi0 = z, hi1 = z, hi2 = z, hi3 = z;
    int i = beg;
    for (; i + 4 <= end; i += 4) {
        uint4 u0 = xw4[csr_src[i] * 16 + lane];
        uint4 u1 = xw4[csr_src[i + 1] * 16 + lane];
        uint4 u2 = xw4[csr_src[i + 2] * 16 + lane];
        uint4 u3 = xw4[csr_src[i + 3] * 16 + lane];
        lo0 += f4_of_bf4(u0.x, u0.y);
        hi0 += f4_of_bf4(u0.z, u0.w);
        lo1 += f4_of_bf4(u1.x, u1.y);
        hi1 += f4_of_bf4(u1.z, u1.w);
        lo2 += f4_of_bf4(u2.x, u2.y);
        hi2 += f4_of_bf4(u2.z, u2.w);
        lo3 += f4_of_bf4(u3.x, u3.y);
        hi3 += f4_of_bf4(u3.z, u3.w);
    }
    for (; i < end; ++i) {
        uint4 u = xw4[csr_src[i] * 16 + lane];
        lo0 += f4_of_bf4(u.x, u.y);
        hi0 += f4_of_bf4(u.z, u.w);
    }
    f4 rlo = (lo0 + lo1) + (lo2 + lo3);
    f4 rhi = (hi0 + hi1) + (hi2 + hi3);
    float cd = c_dst[node];
    f4 blo = b4p[lane * 2];
    f4 bhi = b4p[lane * 2 + 1];
    rlo = rlo * cd + blo;
    rhi = rhi * cd + bhi;
#pragma unroll
    for (int q = 0; q < 4; ++q) {
        rlo[q] = fmaxf(rlo[q], 0.0f);
        rhi[q] = fmaxf(rhi[q], 0.0f);
    }
    us8 o;
    o[0] = bf16_of(rlo.x);
    o[1] = bf16_of(rlo.y);
    o[2] = bf16_of(rlo.z);
    o[3] = bf16_of(rlo.w);
    o[4] = bf16_of(rhi.x);
    o[5] = bf16_of(rhi.y);
    o[6] = bf16_of(rhi.z);
    o[7] = bf16_of(rhi.w);
    return o;
}

// ---------------- hidden gather (layers 2,3): h = bf16(relu(c_dst*gather(xw)+b)) -------------

__global__ __launch_bounds__(256) void gather128_kernel(const int* __restrict__ row_ptr,
                                                        const int* __restrict__ csr_src,
                                                        const ushort* __restrict__ xw,
                                                        const float* __restrict__ c_dst,
                                                        const float* __restrict__ bias,
                                                        ushort* __restrict__ out, int n) {
    int node = blockIdx.x * 16 + (threadIdx.x >> 4);
    int lane = threadIdx.x & 15;
    if (node >= n) return;
    us8 o = gather_node_row(row_ptr, csr_src, (const uint4*)xw, c_dst, (const f4*)bias, node,
                            lane);
    ((us8*)out)[node * 16 + lane] = o;
}

// ---------------- layer-4+5 fused: h4 = relu(c_dst*gather(xw3)+b4) (LDS only),
//                  then xw18b = bf16((h4 @ W5) * c_src) via 2 MFMA groups ----------------

__global__ __launch_bounds__(256) void fused_gather_out18_kernel(
    const int* __restrict__ row_ptr, const int* __restrict__ csr_src,
    const ushort* __restrict__ xw_in, const float* __restrict__ c_dst,
    const float* __restrict__ bias, const ushort* __restrict__ W5t,
    const float* __restrict__ c_src, ushort* __restrict__ xw18b, int n) {
    __shared__ us8 hs[16 * 16];  // 16 nodes x 128 bf16, 16B-unit XOR swizzle
    int t = threadIdx.x;
    int base = blockIdx.x * 16;
    int j = t >> 4, lane = t & 15;
    us8 o = gather_node_row(row_ptr, csr_src, (const uint4*)xw_in, c_dst, (const f4*)bias,
                            base + j, lane);
    hs[j * 16 + (lane ^ j)] = o;
    __syncthreads();
    if (t < 64) {
        int lm = t & 15, lg = t >> 4;
        const s8v* hv = (const s8v*)hs;
        s8v hb0 = hv[lm * 16 + (lg ^ lm)];
        s8v hb1 = hv[lm * 16 + ((4 + lg) ^ lm)];
        s8v hb2 = hv[lm * 16 + ((8 + lg) ^ lm)];
        s8v hb3 = hv[lm * 16 + ((12 + lg) ^ lm)];
        f4 acc0 = {0.f, 0.f, 0.f, 0.f};
        f4 acc1 = acc0;
        const s8v* wp0 = (const s8v*)(W5t + (size_t)lm * HDIM + lg * 8);
        const s8v* wp1 = (const s8v*)(W5t + (size_t)(16 + lm) * HDIM + lg * 8);
        acc0 = __builtin_amdgcn_mfma_f32_16x16x32_bf16(wp0[0], hb0, acc0, 0, 0, 0);
        acc0 = __builtin_amdgcn_mfma_f32_16x16x32_bf16(wp0[4], hb1, acc0, 0, 0, 0);
        acc0 = __builtin_amdgcn_mfma_f32_16x16x32_bf16(wp0[8], hb2, acc0, 0, 0, 0);
        acc0 = __builtin_amdgcn_mfma_f32_16x16x32_bf16(wp0[12], hb3, acc0, 0, 0, 0);
        acc1 = __builtin_amdgcn_mfma_f32_16x16x32_bf16(wp1[0], hb0, acc1, 0, 0, 0);
        acc1 = __builtin_amdgcn_mfma_f32_16x16x32_bf16(wp1[4], hb1, acc1, 0, 0, 0);
        acc1 = __builtin_amdgcn_mfma_f32_16x16x32_bf16(wp1[8], hb2, acc1, 0, 0, 0);
        acc1 = __builtin_amdgcn_mfma_f32_16x16x32_bf16(wp1[12], hb3, acc1, 0, 0, 0);
        int node = base + lm;
        float cs = c_src[node];
        ushort* orow = xw18b + (size_t)node * 32;
        us4 o0, o1;
        o0.x = bf16_of(acc0.x * cs);
        o0.y = bf16_of(acc0.y * cs);
        o0.z = bf16_of(acc0.z * cs);
        o0.w = bf16_of(acc0.w * cs);
        o1.x = bf16_of(acc1.x * cs);
        o1.y = bf16_of(acc1.y * cs);
        o1.z = bf16_of(acc1.z * cs);
        o1.w = bf16_of(acc1.w * cs);
        *(us4*)(orow + lg * 4) = o0;
        *(us4*)(orow + 16 + lg * 4) = o1;
    }
}

// ---------------- output gather: out = c_dst * sum_in(xw18b) + b5, x4 unroll ----------------

__global__ __launch_bounds__(256) void gather18_kernel(const int* __restrict__ row_ptr,
                                                       const int* __restrict__ csr_src,
                                                       const ushort* __restrict__ xw18b,
                                                       const float* __restrict__ c_dst,
                                                       const float* __restrict__ b5,
                                                       float* __restrict__ out, int n) {
    int node = blockIdx.x * 16 + (threadIdx.x >> 4);
    int lane = threadIdx.x & 15;
    if (node >= n) return;
    int beg = row_ptr[node], end = row_ptr[node + 1];
    const uint* x = (const uint*)xw18b;
    float s0 = 0.f, s1 = 0.f, t0 = 0.f, t1 = 0.f;
    float u0a = 0.f, u1a = 0.f, v0a = 0.f, v1a = 0.f;
    int i = beg;
    for (; i + 4 <= end; i += 4) {
        uint a = x[csr_src[i] * 16 + lane];
        uint b = x[csr_src[i + 1] * 16 + lane];
        uint c = x[csr_src[i + 2] * 16 + lane];
        uint d = x[csr_src[i + 3] * 16 + lane];
        s0 += __uint_as_float(a << 16);
        s1 += __uint_as_float(a & 0xFFFF0000u);
        t0 += __uint_as_float(b << 16);
        t1 += __uint_as_float(b & 0xFFFF0000u);
        u0a += __uint_as_float(c << 16);
        u1a += __uint_as_float(c & 0xFFFF0000u);
        v0a += __uint_as_float(d << 16);
        v1a += __uint_as_float(d & 0xFFFF0000u);
    }
    for (; i < end; ++i) {
        uint u = x[csr_src[i] * 16 + lane];
        s0 += __uint_as_float(u << 16);
        s1 += __uint_as_float(u & 0xFFFF0000u);
    }
    if (lane < 9) {
        float cd = c_dst[node];
        float2 bv = ((const float2*)b5)[lane];
        float2 o;
        o.x = ((s0 + t0) + (u0a + v0a)) * cd + bv.x;
        o.y = ((s1 + t1) + (u1a + v1a)) * cd + bv.y;
        ((float2*)(out + (size_t)node * CDIM))[lane] = o;
    }
}

inline size_t align_up(size_t x, size_t a) { return (x + a - 1) & ~(a - 1); }

}  // namespace

extern "C" void kernel_launch(void* const* d_in, const int* in_sizes, int n_in,
                              void* d_out, int out_size, void* d_ws, size_t ws_size,
                              hipStream_t stream) {
    const float* features = (const float*)d_in[0];
    const int* edge_src = (const int*)d_in[1];
    const int* edge_dst = (const int*)d_in[2];
    const float* W1 = (const float*)d_in[3];
    const float* b1 = (const float*)d_in[4];
    const float* W2 = (const float*)d_in[5];
    const float* b2 = (const float*)d_in[6];
    const float* W3 = (const float*)d_in[7];
    const float* b3 = (const float*)d_in[8];
    const float* W4 = (const float*)d_in[9];
    const float* b4 = (const float*)d_in[10];
    const float* W5 = (const float*)d_in[11];
    const float* b5 = (const float*)d_in[12];
    float* out = (float*)d_out;

    const int N = N_NODES;

    // ---- workspace layout ----
    char* base = (char*)d_ws;
    size_t off = 0;
    auto take = [&](size_t bytes) {
        size_t o = off;
        off = align_up(off + bytes, 256);
        return (void*)(base + o);
    };
    uint* deg4 = (uint*)take(NW * sizeof(uint));
    float* c_src = (float*)take(N * sizeof(float));
    float* c_dst = (float*)take(N * sizeof(float));
    int* row_ptr = (int*)take((N + 4) * sizeof(int));
    int* blk_sum = (int*)take(512 * sizeof(int));
    int* csr_src = (int*)take((size_t)N_EDGES * sizeof(int));
    ushort* Wt = (ushort*)take((size_t)3 * HDIM * HDIM * sizeof(ushort));  // bf16 W2-4^T
    ushort* W5t = (ushort*)take((size_t)32 * HDIM * sizeof(ushort));       // bf16 W5^T pad 32
    us8* featb = (us8*)take((size_t)N * sizeof(us8));  // pre-scaled bf16 features (16 B rows)
    float* bufA = (float*)take((size_t)N * HDIM * sizeof(float));
    float* bufB = (float*)take((size_t)N * HDIM * sizeof(float));
    (void)ws_size;
    uint* part_in = (uint*)bufA;
    uint* part_out = part_in + (size_t)S_IN * NW;
    ushort* xw_bf = (ushort*)bufA;   // hidden xw (25.6 MB)
    ushort* h_bf = (ushort*)bufB;    // h (25.6 MB)
    ushort* xw18b = (ushort*)bufB;   // layer-5 rows (6.4 MB, after h is dead)

    // ---- graph preprocessing: atomic-free CSR build via LDS byte-histograms ----
    hist_kernel<<<S_OUT + S_IN + WTB + W5B, 1024, 0, stream>>>(edge_src, edge_dst, part_out,
                                                               part_in, W2, W3, W4, Wt, W5, W5t);
    reduce_kernel<<<RB, 256, 0, stream>>>(part_in, part_out, deg4, c_src, c_dst, blk_sum,
                                          features, featb);
    scan_final_kernel<<<RB, 256, 0, stream>>>(deg4, blk_sum, row_ptr);
    fill_kernel<<<S_IN, 1024, 0, stream>>>(edge_src, edge_dst, part_in, row_ptr, csr_src);

    // ---- layer 1 fused: feat-gather + W1 + W2-MFMA -> xw1 (bufA; part_in dead) ----
    layer1_kernel<<<(N + 63) / 64, 256, 0, stream>>>(row_ptr, csr_src, featb, c_dst, W1, b1, Wt,
                                                     c_src, xw_bf, N);

    // ---- layer 2: gather(xw1)+b2 -> h2 ; W3-MFMA -> xw2 ----
    gather128_kernel<<<N / 16, 256, 0, stream>>>(row_ptr, csr_src, xw_bf, c_dst, b2, h_bf, N);
    gemm128_mfma_kernel<<<(N + 255) / 256, 256, 0, stream>>>(h_bf, Wt + (size_t)1 * HDIM * HDIM,
                                                             c_src, xw_bf, N);
    // ---- layer 3: gather(xw2)+b3 -> h3 ; W4-MFMA -> xw3 ----
    gather128_kernel<<<N / 16, 256, 0, stream>>>(row_ptr, csr_src, xw_bf, c_dst, b3, h_bf, N);
    gemm128_mfma_kernel<<<(N + 255) / 256, 256, 0, stream>>>(h_bf, Wt + (size_t)2 * HDIM * HDIM,
                                                             c_src, xw_bf, N);

    // ---- layer 4 gather + layer 5 transform fused: xw3 (bufA) -> xw18b (bufB) ----
    fused_gather_out18_kernel<<<N / 16, 256, 0, stream>>>(row_ptr, csr_src, xw_bf, c_dst, b4, W5t,
                                                          c_src, xw18b, N);
    // ---- output gather ----
    gather18_kernel<<<N / 16, 256, 0, stream>>>(row_ptr, csr_src, xw18b, c_dst, b5, out, N);
}

// Round 15
// 345.086 us; speedup vs baseline: 1.0613x; 1.0613x over previous
//
#include <hip/hip_runtime.h>

namespace {

constexpr int N_NODES = 100000;
constexpr int N_EDGES = 1600000;
constexpr int HDIM = 128;
constexpr int CDIM = 18;

constexpr int NW = N_NODES / 4;            // 25000 packed-byte words (100 KB LDS)
constexpr int S_IN = 128;                  // dst-histogram slices
constexpr int S_OUT = 64;                  // src-histogram slices
constexpr int EPB_IN = N_EDGES / S_IN;     // 12500
constexpr int EPB_OUT = N_EDGES / S_OUT;   // 25000
constexpr int RB = (NW + 255) / 256;       // reduce/scan blocks (1024 nodes each) = 98
constexpr int WTB = 3 * HDIM * HDIM / 1024;  // Wt conversion blocks (1024 thr) = 48
constexpr int W5B = 32 * HDIM / 1024;        // W5t conversion blocks = 4

using f4 = __attribute__((ext_vector_type(4))) float;
using s8v = __attribute__((ext_vector_type(8))) short;   // 8 bf16 (4 VGPRs), MFMA A/B frag
using us4 = __attribute__((ext_vector_type(4))) unsigned short;
using us8 = __attribute__((ext_vector_type(8))) unsigned short;
using uint = unsigned int;
using ushort = unsigned short;

// bf16 pack/unpack (RNE on pack; unpack is exact bit-splicing)
__device__ __forceinline__ ushort bf16_of(float f) {
    uint u = __float_as_uint(f);
    return (ushort)((u + 0x7FFFu + ((u >> 16) & 1u)) >> 16);
}
__device__ __forceinline__ float f_of_bf(ushort u) {
    return __uint_as_float((uint)u << 16);
}
__device__ __forceinline__ f4 f4_of_bf4(uint lo, uint hi) {
    f4 r;
    r.x = __uint_as_float(lo << 16);
    r.y = __uint_as_float(lo & 0xFFFF0000u);
    r.z = __uint_as_float(hi << 16);
    r.w = __uint_as_float(hi & 0xFFFF0000u);
    return r;
}

// ---------------- histograms + (free-riding) weight conversions ----------------
// Blocks 0..191: packed-byte histograms (100 KB LDS, 1 block/CU).
// Blocks 192..239: W2-4 -> bf16^T. Blocks 240..243: W5 -> bf16^T padded 32x128.

__global__ __launch_bounds__(1024) void hist_kernel(const int* __restrict__ src,
                                                    const int* __restrict__ dst,
                                                    uint* __restrict__ part_out,
                                                    uint* __restrict__ part_in,
                                                    const float* __restrict__ W2,
                                                    const float* __restrict__ W3,
                                                    const float* __restrict__ W4,
                                                    ushort* __restrict__ Wt,
                                                    const float* __restrict__ W5,
                                                    ushort* __restrict__ W5t) {
    int b = blockIdx.x;
    if (b >= S_OUT + S_IN) {
        int cb = b - (S_OUT + S_IN);
        if (cb < WTB) {
            int idx = cb * 1024 + threadIdx.x;  // 48*1024 = 3*128*128
            int which = idx >> 14;
            int r = idx & 16383;
            const float* W = which == 0 ? W2 : (which == 1 ? W3 : W4);
            int nn = r >> 7, k = r & 127;
            Wt[idx] = bf16_of(W[k * HDIM + nn]);
        } else {
            int idx = (cb - WTB) * 1024 + threadIdx.x;  // 4*1024 = 32*128
            int nn = idx >> 7, k = idx & 127;
            W5t[idx] = (nn < CDIM) ? bf16_of(W5[k * CDIM + nn]) : (ushort)0;
        }
        return;
    }
    __shared__ uint hist[NW];
    for (int i = threadIdx.x; i < NW; i += 1024) hist[i] = 0u;
    __syncthreads();
    const int* idx;
    uint* part;
    int beg, cnt;
    if (b < S_OUT) {
        idx = src;
        part = part_out + (size_t)b * NW;
        beg = b * EPB_OUT;
        cnt = EPB_OUT;
    } else {
        int b2 = b - S_OUT;
        idx = dst;
        part = part_in + (size_t)b2 * NW;
        beg = b2 * EPB_IN;
        cnt = EPB_IN;
    }
    for (int i = threadIdx.x; i < cnt; i += 1024) {
        int d = idx[beg + i];
        atomicAdd(&hist[d >> 2], 1u << ((d & 3) * 8));
    }
    __syncthreads();
    for (int i = threadIdx.x; i < NW; i += 1024) part[i] = hist[i];
}

// ---------------- reduce: partials -> per-slice byte offsets (in place) + deg4 + coeffs
//                  + raw per-block sums + featb = bf16(feat * c_src) ----------------

__global__ __launch_bounds__(256) void reduce_kernel(uint* __restrict__ part_in,  // -> off_in
                                                     const uint* __restrict__ part_out,
                                                     uint* __restrict__ deg4,
                                                     float* __restrict__ c_src,
                                                     float* __restrict__ c_dst,
                                                     int* __restrict__ blk_sum,
                                                     const float* __restrict__ feat,
                                                     us8* __restrict__ featb) {
    __shared__ int ssum[256];
    int t = threadIdx.x;
    int w = blockIdx.x * 256 + t;
    uint sin = 0u;
    int tot = 0;
    if (w < NW) {
        for (int s = 0; s < S_IN; ++s) {
            size_t p = (size_t)s * NW + w;
            uint c = part_in[p];
            part_in[p] = sin;  // exclusive prefix over slices, packed bytes
            sin += c;
        }
        uint sout = 0u;
        for (int s = 0; s < S_OUT; ++s) sout += part_out[(size_t)s * NW + w];
        deg4[w] = sin;
        f4 F[6];
        const f4* fp = (const f4*)(feat + (size_t)w * 24);
#pragma unroll
        for (int r = 0; r < 6; ++r) F[r] = fp[r];
#pragma unroll
        for (int q = 0; q < 4; ++q) {
            int v = w * 4 + q;
            int di = (sin >> (q * 8)) & 255;
            int dq = (sout >> (q * 8)) & 255;
            c_dst[v] = di > 0 ? rsqrtf((float)di) : 0.0f;
            float cs = dq > 0 ? rsqrtf((float)dq) : 0.0f;
            c_src[v] = cs;
            us8 o;
#pragma unroll
            for (int k = 0; k < 6; ++k) {
                int idx = q * 6 + k;
                o[k] = bf16_of(F[idx >> 2][idx & 3] * cs);
            }
            o[6] = 0;
            o[7] = 0;
            featb[v] = o;
            tot += di;
        }
    }
    ssum[t] = tot;
    __syncthreads();
    for (int off = 128; off > 0; off >>= 1) {
        if (t < off) ssum[t] += ssum[t + off];
        __syncthreads();
    }
    if (t == 0) blk_sum[blockIdx.x] = ssum[0];
}

// ---------------- scan_final: self-scan raw blk_sums + local scan -> row_ptr (int4) ----------

__global__ __launch_bounds__(256) void scan_final_kernel(const uint* __restrict__ deg4,
                                                         const int* __restrict__ blk_sum,
                                                         int* __restrict__ row_ptr) {
    __shared__ int s[256];
    __shared__ int bs[128];
    int b = blockIdx.x, t = threadIdx.x;
    if (t < 128) bs[t] = (t < RB) ? blk_sum[t] : 0;
    __syncthreads();
    for (int off = 1; off < 128; off <<= 1) {
        int v = (t < 128 && t >= off) ? bs[t - off] : 0;
        __syncthreads();
        if (t < 128) bs[t] += v;
        __syncthreads();
    }
    int blk_off = (b == 0) ? 0 : bs[b - 1];
    int w = b * 256 + t;
    uint d = (w < NW) ? deg4[w] : 0u;
    int d0 = d & 255, d1 = (d >> 8) & 255, d2 = (d >> 16) & 255, d3 = d >> 24;
    int tot = d0 + d1 + d2 + d3;
    s[t] = tot;
    __syncthreads();
    for (int off = 1; off < 256; off <<= 1) {
        int u = (t >= off) ? s[t - off] : 0;
        __syncthreads();
        s[t] += u;
        __syncthreads();
    }
    if (w < NW) {
        int excl = blk_off + s[t] - tot;
        int4 rp;
        rp.x = excl;
        rp.y = excl + d0;
        rp.z = excl + d0 + d1;
        rp.w = excl + d0 + d1 + d2;
        ((int4*)row_ptr)[w] = rp;
    }
    if (b == 0 && t == 0) row_ptr[N_NODES] = N_EDGES;
}

// ---------------- CSR fill, atomic-free: pos = row_ptr + off[slice] + local rank ------------

__global__ __launch_bounds__(1024) void fill_kernel(const int* __restrict__ src,
                                                    const int* __restrict__ dst,
                                                    const uint* __restrict__ off_in,
                                                    const int* __restrict__ row_ptr,
                                                    int* __restrict__ csr_src) {
    __shared__ uint hist[NW];
    for (int i = threadIdx.x; i < NW; i += 1024) hist[i] = 0u;
    __syncthreads();
    int b = blockIdx.x;
    const uint* off = off_in + (size_t)b * NW;
    int beg = b * EPB_IN;
    for (int i = threadIdx.x; i < EPB_IN; i += 1024) {
        int e = beg + i;
        int d = dst[e];
        int sh = (d & 3) * 8;
        uint old = atomicAdd(&hist[d >> 2], 1u << sh);  // LDS, returns old -> unique rank
        int rank = (old >> sh) & 255;
        int base = (off[d >> 2] >> sh) & 255;
        csr_src[row_ptr[d] + base + rank] = src[e];
    }
}

// ---------------- layer 1: agg6 via 16-edge-lane gather of pre-scaled bf16 feat,
//                  shfl-reduce, then h1 = bf16(relu(agg6@W1 + b1))  [R12 form] ----------------

__global__ __launch_bounds__(256) void layer1_kernel(const int* __restrict__ row_ptr,
                                                     const int* __restrict__ csr_src,
                                                     const us8* __restrict__ featb,
                                                     const float* __restrict__ c_dst,
                                                     const float* __restrict__ W1,
                                                     const float* __restrict__ b1,
                                                     ushort* __restrict__ h, int n) {
    __shared__ float xs[16][6];
    int base = blockIdx.x * 16;
    int t = threadIdx.x;
    {
        int j = t >> 4;    // node 0..15
        int lane = t & 15; // edge lane
        int node = base + j;
        int beg = row_ptr[node], end = row_ptr[node + 1];
        float a0 = 0.f, a1 = 0.f, a2 = 0.f, a3 = 0.f, a4 = 0.f, a5 = 0.f;
        for (int i = beg + lane; i < end; i += 16) {
            us8 u = featb[csr_src[i]];  // one 16 B load, pre-scaled by c_src
            a0 += f_of_bf(u[0]);
            a1 += f_of_bf(u[1]);
            a2 += f_of_bf(u[2]);
            a3 += f_of_bf(u[3]);
            a4 += f_of_bf(u[4]);
            a5 += f_of_bf(u[5]);
        }
#pragma unroll
        for (int m = 8; m >= 1; m >>= 1) {
            a0 += __shfl_xor(a0, m);
            a1 += __shfl_xor(a1, m);
            a2 += __shfl_xor(a2, m);
            a3 += __shfl_xor(a3, m);
            a4 += __shfl_xor(a4, m);
            a5 += __shfl_xor(a5, m);
        }
        if (lane == 0) {
            float cd = c_dst[node];
            xs[j][0] = a0 * cd;
            xs[j][1] = a1 * cd;
            xs[j][2] = a2 * cd;
            xs[j][3] = a3 * cd;
            xs[j][4] = a4 * cd;
            xs[j][5] = a5 * cd;
        }
    }
    __syncthreads();
    int f = t & 127;
    int half = t >> 7;
    float w[6];
#pragma unroll
    for (int k = 0; k < 6; ++k) w[k] = W1[k * HDIM + f];
    float bv = b1[f];
#pragma unroll
    for (int j = half * 8; j < half * 8 + 8; ++j) {
        float acc = bv;
#pragma unroll
        for (int k = 0; k < 6; ++k) acc += xs[j][k] * w[k];
        h[(size_t)(base + j) * HDIM + f] = bf16_of(fmaxf(acc, 0.0f));
    }
}

// ---------------- hidden GEMM via MFMA, 64-node blocks, XOR-swizzled W in LDS ----------------
// Swizzle: 16B-unit u = row*16 + c stored at row*16 + (c ^ (row&7)). Naive layout puts all
// 16 lm-lanes (256 B row stride) on the same 4 banks = 16-way conflict; swizzled = 2-way (free).

__global__ __launch_bounds__(256) void gemm128_mfma_kernel(const ushort* __restrict__ h,
                                                           const ushort* __restrict__ Wt,
                                                           const float* __restrict__ c_src,
                                                           ushort* __restrict__ xw, int n) {
    __shared__ ushort wlds[HDIM * HDIM];  // 32 KB
    int t = threadIdx.x;
    {
        const uint4* ws = (const uint4*)Wt;
        uint4* wd = (uint4*)wlds;
#pragma unroll
        for (int r = 0; r < 8; ++r) {
            int u = r * 256 + t;
            int swz = (u & ~15) | ((u & 15) ^ ((u >> 4) & 7));
            wd[swz] = ws[u];
        }
    }
    __syncthreads();
    int w = t >> 6;
    int l = t & 63;
    int base = blockIdx.x * 64 + w * 16;
    if (base >= n) return;
    int lm = l & 15, lg = l >> 4;
    const s8v* hp = (const s8v*)(h + (size_t)(base + lm) * HDIM + lg * 8);
    s8v hb0 = hp[0];
    s8v hb1 = hp[4];
    s8v hb2 = hp[8];
    s8v hb3 = hp[12];
    const s8v* wl = (const s8v*)wlds;
    f4 acc[8];
#pragma unroll
    for (int g = 0; g < 8; ++g) acc[g] = {0.f, 0.f, 0.f, 0.f};
#pragma unroll
    for (int g = 0; g < 8; ++g) {
        int row = g * 16 + lm;
        int rb = row * 16;
        int rk = row & 7;
        acc[g] = __builtin_amdgcn_mfma_f32_16x16x32_bf16(wl[rb + (lg ^ rk)], hb0, acc[g], 0, 0, 0);
        acc[g] = __builtin_amdgcn_mfma_f32_16x16x32_bf16(wl[rb + ((4 + lg) ^ rk)], hb1, acc[g], 0, 0, 0);
        acc[g] = __builtin_amdgcn_mfma_f32_16x16x32_bf16(wl[rb + ((8 + lg) ^ rk)], hb2, acc[g], 0, 0, 0);
        acc[g] = __builtin_amdgcn_mfma_f32_16x16x32_bf16(wl[rb + ((12 + lg) ^ rk)], hb3, acc[g], 0, 0, 0);
    }
    float cs = c_src[base + lm];
    ushort* orow = xw + (size_t)(base + lm) * HDIM;
#pragma unroll
    for (int g = 0; g < 8; ++g) {
        us4 o;
        o.x = bf16_of(acc[g].x * cs);
        o.y = bf16_of(acc[g].y * cs);
        o.z = bf16_of(acc[g].z * cs);
        o.w = bf16_of(acc[g].w * cs);
        *(us4*)(orow + g * 16 + lg * 4) = o;
    }
}

// ================= gather helper =================

__device__ __forceinline__ us8 gather_node_row(const int* __restrict__ row_ptr,
                                               const int* __restrict__ csr_src,
                                               const uint4* __restrict__ xw4,
                                               const float* __restrict__ c_dst,
                                               const f4* __restrict__ b4p, int node, int lane) {
    int beg = row_ptr[node], end = row_ptr[node + 1];
    f4 z = {0.f, 0.f, 0.f, 0.f};
    f4 lo0 = z, lo1 = z, lo2 = z, lo3 = z, hi0 = z, hi1 = z, hi2 = z, hi3 = z;
    int i = beg;
    for (; i + 4 <= end; i += 4) {
        uint4 u0 = xw4[csr_src[i] * 16 + lane];
        uint4 u1 = xw4[csr_src[i + 1] * 16 + lane];
        uint4 u2 = xw4[csr_src[i + 2] * 16 + lane];
        uint4 u3 = xw4[csr_src[i + 3] * 16 + lane];
        lo0 += f4_of_bf4(u0.x, u0.y);
        hi0 += f4_of_bf4(u0.z, u0.w);
        lo1 += f4_of_bf4(u1.x, u1.y);
        hi1 += f4_of_bf4(u1.z, u1.w);
        lo2 += f4_of_bf4(u2.x, u2.y);
        hi2 += f4_of_bf4(u2.z, u2.w);
        lo3 += f4_of_bf4(u3.x, u3.y);
        hi3 += f4_of_bf4(u3.z, u3.w);
    }
    for (; i < end; ++i) {
        uint4 u = xw4[csr_src[i] * 16 + lane];
        lo0 += f4_of_bf4(u.x, u.y);
        hi0 += f4_of_bf4(u.z, u.w);
    }
    f4 rlo = (lo0 + lo1) + (lo2 + lo3);
    f4 rhi = (hi0 + hi1) + (hi2 + hi3);
    float cd = c_dst[node];
    f4 blo = b4p[lane * 2];
    f4 bhi = b4p[lane * 2 + 1];
    rlo = rlo * cd + blo;
    rhi = rhi * cd + bhi;
#pragma unroll
    for (int q = 0; q < 4; ++q) {
        rlo[q] = fmaxf(rlo[q], 0.0f);
        rhi[q] = fmaxf(rhi[q], 0.0f);
    }
    us8 o;
    o[0] = bf16_of(rlo.x);
    o[1] = bf16_of(rlo.y);
    o[2] = bf16_of(rlo.z);
    o[3] = bf16_of(rlo.w);
    o[4] = bf16_of(rhi.x);
    o[5] = bf16_of(rhi.y);
    o[6] = bf16_of(rhi.z);
    o[7] = bf16_of(rhi.w);
    return o;
}

// ---------------- hidden gather (layers 2,3): h = bf16(relu(c_dst*gather(xw)+b)) -------------

__global__ __launch_bounds__(256) void gather128_kernel(const int* __restrict__ row_ptr,
                                                        const int* __restrict__ csr_src,
                                                        const ushort* __restrict__ xw,
                                                        const float* __restrict__ c_dst,
                                                        const float* __restrict__ bias,
                                                        ushort* __restrict__ out, int n) {
    int node = blockIdx.x * 16 + (threadIdx.x >> 4);
    int lane = threadIdx.x & 15;
    if (node >= n) return;
    us8 o = gather_node_row(row_ptr, csr_src, (const uint4*)xw, c_dst, (const f4*)bias, node,
                            lane);
    ((us8*)out)[node * 16 + lane] = o;
}

// ---------------- layer-4+5 fused: h4 = relu(c_dst*gather(xw3)+b4) (LDS only),
//                  then xw18b = bf16((h4 @ W5) * c_src) via 2 MFMA groups ----------------

__global__ __launch_bounds__(256) void fused_gather_out18_kernel(
    const int* __restrict__ row_ptr, const int* __restrict__ csr_src,
    const ushort* __restrict__ xw_in, const float* __restrict__ c_dst,
    const float* __restrict__ bias, const ushort* __restrict__ W5t,
    const float* __restrict__ c_src, ushort* __restrict__ xw18b, int n) {
    __shared__ us8 hs[16 * 16];  // 16 nodes x 128 bf16, 16B-unit XOR swizzle
    int t = threadIdx.x;
    int base = blockIdx.x * 16;
    int j = t >> 4, lane = t & 15;
    us8 o = gather_node_row(row_ptr, csr_src, (const uint4*)xw_in, c_dst, (const f4*)bias,
                            base + j, lane);
    hs[j * 16 + (lane ^ j)] = o;
    __syncthreads();
    if (t < 64) {
        int lm = t & 15, lg = t >> 4;
        const s8v* hv = (const s8v*)hs;
        s8v hb0 = hv[lm * 16 + (lg ^ lm)];
        s8v hb1 = hv[lm * 16 + ((4 + lg) ^ lm)];
        s8v hb2 = hv[lm * 16 + ((8 + lg) ^ lm)];
        s8v hb3 = hv[lm * 16 + ((12 + lg) ^ lm)];
        f4 acc0 = {0.f, 0.f, 0.f, 0.f};
        f4 acc1 = acc0;
        const s8v* wp0 = (const s8v*)(W5t + (size_t)lm * HDIM + lg * 8);
        const s8v* wp1 = (const s8v*)(W5t + (size_t)(16 + lm) * HDIM + lg * 8);
        acc0 = __builtin_amdgcn_mfma_f32_16x16x32_bf16(wp0[0], hb0, acc0, 0, 0, 0);
        acc0 = __builtin_amdgcn_mfma_f32_16x16x32_bf16(wp0[4], hb1, acc0, 0, 0, 0);
        acc0 = __builtin_amdgcn_mfma_f32_16x16x32_bf16(wp0[8], hb2, acc0, 0, 0, 0);
        acc0 = __builtin_amdgcn_mfma_f32_16x16x32_bf16(wp0[12], hb3, acc0, 0, 0, 0);
        acc1 = __builtin_amdgcn_mfma_f32_16x16x32_bf16(wp1[0], hb0, acc1, 0, 0, 0);
        acc1 = __builtin_amdgcn_mfma_f32_16x16x32_bf16(wp1[4], hb1, acc1, 0, 0, 0);
        acc1 = __builtin_amdgcn_mfma_f32_16x16x32_bf16(wp1[8], hb2, acc1, 0, 0, 0);
        acc1 = __builtin_amdgcn_mfma_f32_16x16x32_bf16(wp1[12], hb3, acc1, 0, 0, 0);
        int node = base + lm;
        float cs = c_src[node];
        ushort* orow = xw18b + (size_t)node * 32;
        us4 o0, o1;
        o0.x = bf16_of(acc0.x * cs);
        o0.y = bf16_of(acc0.y * cs);
        o0.z = bf16_of(acc0.z * cs);
        o0.w = bf16_of(acc0.w * cs);
        o1.x = bf16_of(acc1.x * cs);
        o1.y = bf16_of(acc1.y * cs);
        o1.z = bf16_of(acc1.z * cs);
        o1.w = bf16_of(acc1.w * cs);
        *(us4*)(orow + lg * 4) = o0;
        *(us4*)(orow + 16 + lg * 4) = o1;
    }
}

// ---------------- output gather: out = c_dst * sum_in(xw18b) + b5, x4 unroll ----------------

__global__ __launch_bounds__(256) void gather18_kernel(const int* __restrict__ row_ptr,
                                                       const int* __restrict__ csr_src,
                                                       const ushort* __restrict__ xw18b,
                                                       const float* __restrict__ c_dst,
                                                       const float* __restrict__ b5,
                                                       float* __restrict__ out, int n) {
    int node = blockIdx.x * 16 + (threadIdx.x >> 4);
    int lane = threadIdx.x & 15;
    if (node >= n) return;
    int beg = row_ptr[node], end = row_ptr[node + 1];
    const uint* x = (const uint*)xw18b;
    float s0 = 0.f, s1 = 0.f, t0 = 0.f, t1 = 0.f;
    float u0a = 0.f, u1a = 0.f, v0a = 0.f, v1a = 0.f;
    int i = beg;
    for (; i + 4 <= end; i += 4) {
        uint a = x[csr_src[i] * 16 + lane];
        uint b = x[csr_src[i + 1] * 16 + lane];
        uint c = x[csr_src[i + 2] * 16 + lane];
        uint d = x[csr_src[i + 3] * 16 + lane];
        s0 += __uint_as_float(a << 16);
        s1 += __uint_as_float(a & 0xFFFF0000u);
        t0 += __uint_as_float(b << 16);
        t1 += __uint_as_float(b & 0xFFFF0000u);
        u0a += __uint_as_float(c << 16);
        u1a += __uint_as_float(c & 0xFFFF0000u);
        v0a += __uint_as_float(d << 16);
        v1a += __uint_as_float(d & 0xFFFF0000u);
    }
    for (; i < end; ++i) {
        uint u = x[csr_src[i] * 16 + lane];
        s0 += __uint_as_float(u << 16);
        s1 += __uint_as_float(u & 0xFFFF0000u);
    }
    if (lane < 9) {
        float cd = c_dst[node];
        float2 bv = ((const float2*)b5)[lane];
        float2 o;
        o.x = ((s0 + t0) + (u0a + v0a)) * cd + bv.x;
        o.y = ((s1 + t1) + (u1a + v1a)) * cd + bv.y;
        ((float2*)(out + (size_t)node * CDIM))[lane] = o;
    }
}

inline size_t align_up(size_t x, size_t a) { return (x + a - 1) & ~(a - 1); }

}  // namespace

extern "C" void kernel_launch(void* const* d_in, const int* in_sizes, int n_in,
                              void* d_out, int out_size, void* d_ws, size_t ws_size,
                              hipStream_t stream) {
    const float* features = (const float*)d_in[0];
    const int* edge_src = (const int*)d_in[1];
    const int* edge_dst = (const int*)d_in[2];
    const float* W1 = (const float*)d_in[3];
    const float* b1 = (const float*)d_in[4];
    const float* W2 = (const float*)d_in[5];
    const float* b2 = (const float*)d_in[6];
    const float* W3 = (const float*)d_in[7];
    const float* b3 = (const float*)d_in[8];
    const float* W4 = (const float*)d_in[9];
    const float* b4 = (const float*)d_in[10];
    const float* W5 = (const float*)d_in[11];
    const float* b5 = (const float*)d_in[12];
    float* out = (float*)d_out;

    const int N = N_NODES;

    // ---- workspace layout ----
    char* base = (char*)d_ws;
    size_t off = 0;
    auto take = [&](size_t bytes) {
        size_t o = off;
        off = align_up(off + bytes, 256);
        return (void*)(base + o);
    };
    uint* deg4 = (uint*)take(NW * sizeof(uint));
    float* c_src = (float*)take(N * sizeof(float));
    float* c_dst = (float*)take(N * sizeof(float));
    int* row_ptr = (int*)take((N + 4) * sizeof(int));
    int* blk_sum = (int*)take(512 * sizeof(int));
    int* csr_src = (int*)take((size_t)N_EDGES * sizeof(int));
    ushort* Wt = (ushort*)take((size_t)3 * HDIM * HDIM * sizeof(ushort));  // bf16 W2-4^T
    ushort* W5t = (ushort*)take((size_t)32 * HDIM * sizeof(ushort));       // bf16 W5^T pad 32
    us8* featb = (us8*)take((size_t)N * sizeof(us8));  // pre-scaled bf16 features (16 B rows)
    float* bufA = (float*)take((size_t)N * HDIM * sizeof(float));
    float* bufB = (float*)take((size_t)N * HDIM * sizeof(float));
    (void)ws_size;
    uint* part_in = (uint*)bufA;
    uint* part_out = part_in + (size_t)S_IN * NW;
    ushort* xw_bf = (ushort*)bufA;   // hidden xw (25.6 MB)
    ushort* h_bf = (ushort*)bufB;    // h (25.6 MB)
    ushort* xw18b = (ushort*)bufB;   // layer-5 rows (6.4 MB, after h is dead)

    // ---- graph preprocessing: atomic-free CSR build via LDS byte-histograms ----
    hist_kernel<<<S_OUT + S_IN + WTB + W5B, 1024, 0, stream>>>(edge_src, edge_dst, part_out,
                                                               part_in, W2, W3, W4, Wt, W5, W5t);
    reduce_kernel<<<RB, 256, 0, stream>>>(part_in, part_out, deg4, c_src, c_dst, blk_sum,
                                          features, featb);
    scan_final_kernel<<<RB, 256, 0, stream>>>(deg4, blk_sum, row_ptr);
    fill_kernel<<<S_IN, 1024, 0, stream>>>(edge_src, edge_dst, part_in, row_ptr, csr_src);

    // ---- layer 1: feat-gather + 6->128 GEMM -> h1 (bufB) ----
    layer1_kernel<<<N / 16, 256, 0, stream>>>(row_ptr, csr_src, featb, c_dst, W1, b1, h_bf, N);

    // ---- layers 2-4 transforms + layers 2,3 gathers ----
    const float* bs[2] = {b2, b3};
    for (int l = 0; l < 3; ++l) {
        gemm128_mfma_kernel<<<(N + 63) / 64, 256, 0, stream>>>(h_bf, Wt + (size_t)l * HDIM * HDIM,
                                                               c_src, xw_bf, N);
        if (l < 2)
            gather128_kernel<<<N / 16, 256, 0, stream>>>(row_ptr, csr_src, xw_bf, c_dst, bs[l],
                                                         h_bf, N);
    }

    // ---- layer 4 gather + layer 5 transform fused: xw3 (bufA) -> xw18b (bufB) ----
    fused_gather_out18_kernel<<<N / 16, 256, 0, stream>>>(row_ptr, csr_src, xw_bf, c_dst, b4, W5t,
                                                          c_src, xw18b, N);
    // ---- output gather ----
    gather18_kernel<<<N / 16, 256, 0, stream>>>(row_ptr, csr_src, xw18b, c_dst, b5, out, N);
}